// Round 11
// baseline (633.686 us; speedup 1.0000x reference)
//
#include <hip/hip_runtime.h>

#define SEQL 1024
#define DMODEL 512
#define DINNER 1024
#define NROWS 8192
#define SEG 64
#define NSEG 16
#define LOG2E 1.4426950408889634f

typedef unsigned short u16;
typedef unsigned int u32;
using bf16x8 = __attribute__((ext_vector_type(8))) short;
using f32x4  = __attribute__((ext_vector_type(4))) float;
using u16x4  = __attribute__((ext_vector_type(4))) unsigned short;
using u16x8  = __attribute__((ext_vector_type(8))) unsigned short;

__device__ __forceinline__ float rcp_fast(float x){ return __builtin_amdgcn_rcpf(x); }
__device__ __forceinline__ float exp_fast(float x){ return __expf(x); }
#if __has_builtin(__builtin_amdgcn_exp2f)
__device__ __forceinline__ float exp2_fast(float x){ return __builtin_amdgcn_exp2f(x); }
#else
__device__ __forceinline__ float exp2_fast(float x){ return __expf(x*0.6931471805599453f); }
#endif
__device__ __forceinline__ float sigmoid_f(float x){ return rcp_fast(1.f+exp_fast(-x)); }
__device__ __forceinline__ float softplus_f(float x){ return fmaxf(x,0.f)+__logf(1.f+exp_fast(-fabsf(x))); }
__device__ __forceinline__ float gelu_f(float x){
  float u2 = 1.5957691216057308f*(x+0.044715f*x*x*x);
  float t = 1.f - 2.f*rcp_fast(1.f+exp_fast(u2));
  return 0.5f*x*(1.f+t);
}
__device__ __forceinline__ u16 f2bf(float f){
  u32 u = __builtin_bit_cast(u32, f);
  return (u16)((u + 0x7FFFu + ((u>>16)&1u)) >> 16);
}
__device__ __forceinline__ float bf2f(u16 h){
  return __builtin_bit_cast(float, (u32)h << 16);
}

// async global -> LDS, 16B per lane (LDS dest must be linear in lane order)
typedef __attribute__((address_space(1))) const void g_void;
typedef __attribute__((address_space(3))) void l_void;
__device__ __forceinline__ void gl_lds16(const void* g, void* l){
  __builtin_amdgcn_global_load_lds((g_void*)g, (l_void*)l, 16, 0, 0);
}

// ---------------- weight transpose+cvt: [K,N] fp32 -> [N,K] bf16 ---------------
struct WtDesc { const float* src; u16* dst; int K; int N; int t0; };
struct WtArgs { WtDesc d[11]; };

__global__ __launch_bounds__(256) void wt_k(WtArgs a)
{
  __shared__ float t[64][65];
  int bid = blockIdx.x;
  int i = 0;
  #pragma unroll
  for (int j=1;j<11;++j) if (bid >= a.d[j].t0) i = j;
  const float* src = a.d[i].src; u16* dst = a.d[i].dst;
  int K = a.d[i].K, N = a.d[i].N;
  int ntN = (N+63)>>6;
  int loc = bid - a.d[i].t0;
  int k0 = (loc / ntN)*64, n0 = (loc % ntN)*64;
  int tr = threadIdx.x>>4, tc = threadIdx.x&15;
  #pragma unroll
  for (int p=0;p<4;++p) {
    int r = p*16 + tr; int c = tc*4;
    if (n0 + c < N) {
      float4 v = *(const float4*)(src + (size_t)(k0+r)*N + n0 + c);
      t[r][c]=v.x; t[r][c+1]=v.y; t[r][c+2]=v.z; t[r][c+3]=v.w;
    }
  }
  __syncthreads();
  #pragma unroll
  for (int p=0;p<4;++p) {
    int n = p*16 + tr; int k = tc*4;
    if (n0 + n < N) {
      u16x4 o = { f2bf(t[k][n]), f2bf(t[k+1][n]), f2bf(t[k+2][n]), f2bf(t[k+3][n]) };
      *(u16x4*)(dst + (size_t)(n0+n)*K + k0 + k) = o;
    }
  }
}

// ---------------- bias concat for QKV -----------------------------------------
__global__ __launch_bounds__(256) void pack3_k(const float* a, const float* b,
                                               const float* c, float* o)
{
  int t = blockIdx.x*256 + threadIdx.x;
  if (t < 512) o[t] = a[t];
  else if (t < 1024) o[t] = b[t-512];
  else if (t < 1536) o[t] = c[t-1024];
}

// ---------------- LayerNorm (D=512): one wave per row, no barriers -------------
// AM: 0 = a f32, no b ; 1 = a f32 + b bf16 ; 2 = a bf16 + b f32
template<int AM>
__global__ __launch_bounds__(256) void ln_k(const void* av, const void* bv, float* resid,
                                            const float* g, const float* beta,
                                            float* outf, u16* outb)
{
  const int lane = threadIdx.x & 63;
  const int row = (blockIdx.x<<2) + (threadIdx.x>>6);
  size_t off = (size_t)row*DMODEL + lane*8;
  float v[8];
  if (AM==2) {
    u16x8 va = *(const u16x8*)((const u16*)av + off);
    #pragma unroll
    for (int i=0;i<8;++i) v[i] = bf2f(va[i]);
  } else {
    float4 a0 = *(const float4*)((const float*)av + off);
    float4 a1 = *(const float4*)((const float*)av + off + 4);
    v[0]=a0.x; v[1]=a0.y; v[2]=a0.z; v[3]=a0.w;
    v[4]=a1.x; v[5]=a1.y; v[6]=a1.z; v[7]=a1.w;
  }
  if (AM==1) {
    u16x8 wb = *(const u16x8*)((const u16*)bv + off);
    #pragma unroll
    for (int i=0;i<8;++i) v[i] += bf2f(wb[i]);
  } else if (AM==2) {
    float4 b0 = *(const float4*)((const float*)bv + off);
    float4 b1 = *(const float4*)((const float*)bv + off + 4);
    v[0]+=b0.x; v[1]+=b0.y; v[2]+=b0.z; v[3]+=b0.w;
    v[4]+=b1.x; v[5]+=b1.y; v[6]+=b1.z; v[7]+=b1.w;
  }
  if (resid) {
    float4 r0 = {v[0],v[1],v[2],v[3]};
    float4 r1 = {v[4],v[5],v[6],v[7]};
    *(float4*)(resid + off) = r0;
    *(float4*)(resid + off + 4) = r1;
  }
  float s=0.f, q=0.f;
  #pragma unroll
  for (int i=0;i<8;++i){ s += v[i]; q = fmaf(v[i], v[i], q); }
  #pragma unroll
  for (int o=1;o<64;o<<=1){ s += __shfl_xor(s,o); q += __shfl_xor(q,o); }
  float mean = s*(1.f/512.f);
  float var  = q*(1.f/512.f) - mean*mean;
  float rstd = rsqrtf(var + 1e-5f);
  int c = lane*8;
  float4 g0 = *(const float4*)(g+c);
  float4 g1 = *(const float4*)(g+c+4);
  float4 b0 = *(const float4*)(beta+c);
  float4 b1 = *(const float4*)(beta+c+4);
  float gg[8] = {g0.x,g0.y,g0.z,g0.w,g1.x,g1.y,g1.z,g1.w};
  float bb[8] = {b0.x,b0.y,b0.z,b0.w,b1.x,b1.y,b1.z,b1.w};
  float o8[8];
  #pragma unroll
  for (int i=0;i<8;++i) o8[i] = (v[i]-mean)*rstd*gg[i] + bb[i];
  if (outf) {
    float4 f0 = {o8[0],o8[1],o8[2],o8[3]};
    float4 f1 = {o8[4],o8[5],o8[6],o8[7]};
    *(float4*)(outf + off) = f0;
    *(float4*)(outf + off + 4) = f1;
  }
  if (outb) {
    u16x8 ob = { f2bf(o8[0]),f2bf(o8[1]),f2bf(o8[2]),f2bf(o8[3]),
                 f2bf(o8[4]),f2bf(o8[5]),f2bf(o8[6]),f2bf(o8[7]) };
    *(u16x8*)(outb + off) = ob;
  }
}

// ---------------- bf16 MFMA GEMM, TMxTN tile, BK=32, dbuf LDS, 1 barrier/step --
// EPI: 3 gelu(x+bias) bf16, 5 x+bias+p0 f32, 6 gate fusion (bf16 p0/p1, f32 p2) f32,
//      7 bf16, 8 bf16+bias,
//      11 QKV fused (cols 0-1023 -> Q/K bf16 + bias; 1024-1535 -> V transposed to aux),
//      12 BC|delta fused (cols 0-31 -> Cf raw f32; 32-1055 -> softplus+bias -> bf16 aux)
// BMODE: 0 plain, 3 stitched A|A2 (K=1024)
// TM/TN: 128 or 64 (waves 2x2; per-wave sub-tile TM/2 x TN/2)
template<int EPI, int BMODE, int TM, int TN>
__global__ __launch_bounds__(256) void mm_k(
    const u16* Ab, int lda, const u16* Bb, int ldb,
    void* Cv, int ldc, int M, int N, int K,
    const float* bias, const float* p0, const float* p1, const float* p2,
    const u16* A2b, u16* aux)
{
  constexpr int NI = TM/32;
  constexpr int NJ = TN/32;
  __shared__ u16 As[2][TM][32];
  __shared__ u16 Bs[2][TN][32];
  const int tid = threadIdx.x;
  const int bx = blockIdx.x, by = blockIdx.y;
  float* Cf = (float*)Cv;
  u16* Cb = (u16*)Cv;
  const int row0 = by*TM, col0 = bx*TN;
  const int sr = tid>>2, sc = tid&3;
  const int wv = tid>>6, lane = tid&63;
  const int wr = wv>>1, wc = wv&1;
  const int lr = lane&15, lk = (lane>>4)*8;
  const int lq = lane>>4;

  f32x4 acc[NI][NJ];
  #pragma unroll
  for (int i=0;i<NI;++i)
    #pragma unroll
    for (int j=0;j<NJ;++j)
      acc[i][j] = (f32x4){0.f,0.f,0.f,0.f};

  auto stage = [&](int buf, int k0){
    #pragma unroll
    for (int h=0; h<TM/64; ++h) {
      int row = sr + h*64;
      const u16* src;
      if (BMODE==3) {
        int kk = k0 + sc*8;
        src = (kk < 512) ? Ab + (size_t)(row0+row)*512 + kk
                         : A2b + (size_t)(row0+row)*512 + (kk-512);
      } else {
        src = Ab + (size_t)(row0+row)*lda + k0 + sc*8;
      }
      gl_lds16(src, &As[buf][row][sc*8]);
    }
    #pragma unroll
    for (int h=0; h<TN/64; ++h) {
      int rowb = sr + h*64;
      gl_lds16(Bb + (size_t)(col0+rowb)*ldb + k0 + sc*8, &Bs[buf][rowb][sc*8]);
    }
  };

  const int nt = K/32;
  stage(0, 0);
  __syncthreads();
  for (int t=0; t<nt; ++t) {
    int buf = t&1;
    if (t+1 < nt) stage(buf^1, (t+1)*32);
    bf16x8 fa[NI], fb[NJ];
    #pragma unroll
    for (int i=0;i<NI;++i) fa[i] = *(const bf16x8*)&As[buf][wr*(TM/2) + i*16 + lr][lk];
    #pragma unroll
    for (int j=0;j<NJ;++j) fb[j] = *(const bf16x8*)&Bs[buf][wc*(TN/2) + j*16 + lr][lk];
    #pragma unroll
    for (int i=0;i<NI;++i)
      #pragma unroll
      for (int j=0;j<NJ;++j)
        acc[i][j] = __builtin_amdgcn_mfma_f32_16x16x32_bf16(fa[i], fb[j], acc[i][j], 0,0,0);
    __syncthreads();
  }

  #pragma unroll
  for (int i=0;i<NI;++i) {
    #pragma unroll
    for (int j=0;j<NJ;++j) {
      int col = col0 + wc*(TN/2) + j*16 + lr;
      if (col >= N) continue;
      int rowbase = row0 + wr*(TM/2) + i*16 + lq*4;
      f32x4 v4 = acc[i][j];
      if (EPI==11 && col >= 1024) {
        int c2 = col-1024;
        int b2 = rowbase >> 10;
        int l2 = rowbase & 1023;
        float bv = bias[col];
        u16x4 pk = { f2bf(v4[0]+bv), f2bf(v4[1]+bv), f2bf(v4[2]+bv), f2bf(v4[3]+bv) };
        *(u16x4*)(aux + (size_t)b2*DMODEL*SEQL + (size_t)c2*SEQL + l2) = pk;
        continue;
      }
      #pragma unroll
      for (int r=0;r<4;++r) {
        int row = rowbase + r;
        size_t idx = (size_t)row*ldc + col;
        float v = v4[r];
        if (EPI==3) Cb[idx] = f2bf(gelu_f(v + bias[col]));
        else if (EPI==5) Cf[idx] = v + bias[col] + p0[idx];
        else if (EPI==6) {
          float g = sigmoid_f(v + bias[col]);
          float m  = bf2f(((const u16*)p0)[idx]);
          float at = bf2f(((const u16*)p1)[idx]);
          Cf[idx] = p2[idx] + at + g*m + (1.f-g)*at;
        }
        else if (EPI==7) Cb[idx] = f2bf(v);
        else if (EPI==8) Cb[idx] = f2bf(v + bias[col]);
        else if (EPI==11) {
          size_t i2 = (size_t)(col>>9)*4194304 + (size_t)row*512 + (col&511);
          Cb[i2] = f2bf(v + bias[col]);
        }
        else if (EPI==12) {
          if (col < 32) Cf[(size_t)row*32 + col] = v;
          else aux[(size_t)row*1024 + (col-32)] = f2bf(softplus_f(v + bias[col-32]));
        }
      }
    }
  }
}

// ---------------- fused attention: 16-row q-tiles, two k-halves ----------------
// grid (qt=64, bh=64), 256 thr (4 waves). Scores: wave w covers k-cols w*256..+256.
// P handled in two 512-col halves in LDS (19.5 KB total); AW dump issued BEFORE PV
// so stores drain under MFMA. Lower VGPR (acc[16]) -> 3 waves/SIMD.
__global__ __launch_bounds__(256) void attn_k(const u16* Qb, const u16* Kb,
                                              const u16* VTb, float* AW, u16* Hbb)
{
  __shared__ u16 Qs[16][72];
  __shared__ u16 Ps[16][520];
  __shared__ float smax[4][16];
  __shared__ float ssum[4][16];

  const int tid = threadIdx.x;
  const int w = tid>>6, lane = tid&63;
  const int qt = blockIdx.x, bh = blockIdx.y;
  const int b = bh>>3, h = bh&7;
  const int q0 = qt*16;
  const int lr = lane&15, lg = lane>>4;
  const int rw = lg*4;

  {
    int r = tid>>4, c = (tid&15)*4;
    const u16* src = Qb + ((size_t)(b*1024 + q0 + r))*512 + h*64 + c;
    *(u16x4*)&Qs[r][c] = *(const u16x4*)src;
  }
  __syncthreads();

  f32x4 acc[16];
  #pragma unroll
  for (int j=0;j<16;++j) acc[j] = (f32x4){0.f,0.f,0.f,0.f};
  bf16x8 fa0 = *(const bf16x8*)&Qs[lr][lg*8];
  bf16x8 fa1 = *(const bf16x8*)&Qs[lr][32+lg*8];
  const u16* Kbase = Kb + ((size_t)(b*1024 + w*256))*512 + h*64;
  __builtin_amdgcn_s_setprio(1);
  #pragma unroll
  for (int j=0;j<16;++j){
    const u16* krow = Kbase + (size_t)(j*16 + lr)*512 + lg*8;
    bf16x8 fb0 = *(const bf16x8*)krow;
    bf16x8 fb1 = *(const bf16x8*)(krow+32);
    acc[j] = __builtin_amdgcn_mfma_f32_16x16x32_bf16(fa0, fb0, acc[j], 0,0,0);
    acc[j] = __builtin_amdgcn_mfma_f32_16x16x32_bf16(fa1, fb1, acc[j], 0,0,0);
  }
  __builtin_amdgcn_s_setprio(0);

  float mg[4] = {-1e30f,-1e30f,-1e30f,-1e30f};
  #pragma unroll
  for (int j=0;j<16;++j)
    #pragma unroll
    for (int r=0;r<4;++r) mg[r]=fmaxf(mg[r],acc[j][r]);
  #pragma unroll
  for (int o=1;o<16;o<<=1)
    #pragma unroll
    for (int r=0;r<4;++r) mg[r]=fmaxf(mg[r],__shfl_xor(mg[r],o));
  if (lr==0){
    #pragma unroll
    for (int r=0;r<4;++r) smax[w][rw+r]=mg[r];
  }
  __syncthreads();
  #pragma unroll
  for (int r=0;r<4;++r)
    mg[r] = fmaxf(fmaxf(smax[0][rw+r],smax[1][rw+r]),fmaxf(smax[2][rw+r],smax[3][rw+r]));
  const float cs = 0.125f*LOG2E;
  float sg[4]={0.f,0.f,0.f,0.f};
  #pragma unroll
  for (int j=0;j<16;++j)
    #pragma unroll
    for (int r=0;r<4;++r){
      acc[j][r]=exp2_fast((acc[j][r]-mg[r])*cs); sg[r]+=acc[j][r];
    }
  #pragma unroll
  for (int o=1;o<16;o<<=1)
    #pragma unroll
    for (int r=0;r<4;++r) sg[r]+=__shfl_xor(sg[r],o);
  if (lr==0){
    #pragma unroll
    for (int r=0;r<4;++r) ssum[w][rw+r]=sg[r];
  }
  __syncthreads();
  float ig[4];
  #pragma unroll
  for (int r=0;r<4;++r)
    ig[r] = rcp_fast(ssum[0][rw+r]+ssum[1][rw+r]+ssum[2][rw+r]+ssum[3][rw+r]);

  f32x4 av = (f32x4){0.f,0.f,0.f,0.f};
  const u16* Vbase = VTb + (size_t)b*524288 + (size_t)(h*64 + w*16 + lr)*1024;

  #pragma unroll
  for (int half=0; half<2; ++half){
    if ((w>>1) == half) {
      #pragma unroll
      for (int j=0;j<16;++j){
        int col = (w&1)*256 + j*16 + lr;
        #pragma unroll
        for (int r=0;r<4;++r)
          Ps[rw+r][col] = f2bf(acc[j][r]*ig[r]);
      }
    }
    __syncthreads();
    // AW dump first (stores drain under the PV MFMAs): 16 rows x 512 f32
    {
      float* awbase = AW + (size_t)bh*1048576 + (size_t)q0*1024 + half*512;
      int rowh = tid>>7;
      int c = (tid&127)*4;
      #pragma unroll
      for (int it=0; it<8; ++it) {
        int r = it*2 + rowh;
        u16x4 pv = *(const u16x4*)&Ps[r][c];
        float4 f0 = { bf2f(pv[0]), bf2f(pv[1]), bf2f(pv[2]), bf2f(pv[3]) };
        *(float4*)(awbase + (size_t)r*1024 + c) = f0;
      }
    }
    // PV partial over this half's 512 k-cols (wave w owns d-cols w*16..+16)
    __builtin_amdgcn_s_setprio(1);
    #pragma unroll
    for (int ks=0; ks<16; ++ks){
      bf16x8 fb  = *(const bf16x8*)(Vbase + half*512 + ks*32 + lg*8);
      bf16x8 pa  = *(const bf16x8*)&Ps[lr][ks*32 + lg*8];
      av = __builtin_amdgcn_mfma_f32_16x16x32_bf16(pa, fb, av, 0,0,0);
    }
    __builtin_amdgcn_s_setprio(0);
    if (half==0) __syncthreads();   // WAR guard before half-1 P store
  }

  u16* ob = Hbb + ((size_t)(b*1024 + q0))*512 + h*64 + w*16 + lr;
  #pragma unroll
  for (int r=0;r<4;++r)
    ob[(size_t)(rw+r)*512] = f2bf(av[r]);
}

// ---------------- causal depthwise conv (D_CONV=4) + SiLU, bf16 in/out ---------
__global__ __launch_bounds__(256) void conv_k(const u16* xrb, const float* cw,
                                              const float* cb, u16* xcb)
{
  int t = blockIdx.x*256 + threadIdx.x;
  int d = (t & 255)*4;
  int row = t >> 8;
  int l = row & (SEQL-1);
  const u16* xmb = xrb + (size_t)(row - l)*2048 + d;
  float wv[4][4];
  #pragma unroll
  for (int dd=0; dd<4; ++dd){
    float4 w = *(const float4*)(cw + (size_t)(d+dd)*4);
    wv[dd][0]=w.x; wv[dd][1]=w.y; wv[dd][2]=w.z; wv[dd][3]=w.w;
  }
  float4 acc = *(const float4*)(cb + d);
  #pragma unroll
  for (int k=0;k<4;++k){
    int ls = l + k - 3;
    if (ls >= 0) {
      u16x4 xv = *(const u16x4*)(xmb + (size_t)ls*2048);
      acc.x += wv[0][k]*bf2f(xv[0]);
      acc.y += wv[1][k]*bf2f(xv[1]);
      acc.z += wv[2][k]*bf2f(xv[2]);
      acc.w += wv[3][k]*bf2f(xv[3]);
    }
  }
  float sx = acc.x*rcp_fast(1.f+exp_fast(-acc.x));
  float sy = acc.y*rcp_fast(1.f+exp_fast(-acc.y));
  float sz = acc.z*rcp_fast(1.f+exp_fast(-acc.z));
  float sw = acc.w*rcp_fast(1.f+exp_fast(-acc.w));
  size_t off = (size_t)row*DINNER + d;
  u16x4 ob = { f2bf(sx), f2bf(sy), f2bf(sz), f2bf(sw) };
  *(u16x4*)(xcb + off) = ob;
}

// ---------------- selective scan, chunked two-pass -----------------------------
__global__ __launch_bounds__(256) void scan1_k(const u16* dtb, const u16* ub,
                                               const float* bc, const float* A_log,
                                               float* Pq)
{
  const int tid = threadIdx.x;
  const int d   = blockIdx.x*256 + tid;
  const int seg = blockIdx.y;
  const int b   = blockIdx.z;
  const int l0  = seg*SEG;

  __shared__ float BCs[SEG*32];
  {
    const float4* src = (const float4*)(bc + ((size_t)b*SEQL + l0)*32);
    float4* dst = (float4*)BCs;
    dst[tid]     = src[tid];
    dst[tid+256] = src[tid+256];
  }
  float As2[16];
  #pragma unroll
  for (int s=0;s<16;++s) As2[s] = -expf(A_log[s]) * LOG2E;
  __syncthreads();

  float h[16], P[16];
  #pragma unroll
  for (int s=0;s<16;++s){ h[s]=0.f; P[s]=1.f; }

  size_t base = ((size_t)b*SEQL + l0)*DINNER + d;
  const u16* pdt = dtb + base;
  const u16* pu  = ub  + base;

  u16 dpf[8], upf[8];
  #pragma unroll
  for (int j=0;j<8;++j){ dpf[j]=pdt[(size_t)j*DINNER]; upf[j]=pu[(size_t)j*DINNER]; }
  const u16* pdt_f = pdt + (size_t)8*DINNER;
  const u16* pu_f  = pu  + (size_t)8*DINNER;

  for (int l=0; l<SEG; l+=8) {
    bool pf = (l+8 < SEG);
    #pragma unroll
    for (int j=0;j<8;++j) {
      float dt = bf2f(dpf[j]), u = bf2f(upf[j]);
      if (pf) { dpf[j] = *pdt_f; upf[j] = *pu_f; }
      pdt_f += DINNER; pu_f += DINNER;
      float dtu = dt*u;
      const float* Bs = &BCs[(l+j)*32];
      #pragma unroll
      for (int s=0;s<16;++s) {
        float dA = exp2_fast(dt*As2[s]);
        P[s] *= dA;
        h[s] = fmaf(h[s], dA, dtu*Bs[s]);
      }
    }
  }
  float* out = Pq + (((size_t)b*NSEG + seg)*32)*1024 + d;
  #pragma unroll
  for (int s=0;s<16;++s) {
    out[(size_t)s*1024]      = P[s];
    out[(size_t)(16+s)*1024] = h[s];
  }
}

__global__ __launch_bounds__(256) void scan2_k(const u16* dtb, const u16* ub,
                                               const float* bc, const u16* xrb,
                                               const float* A_log, const float* Dp,
                                               const float* Pq, u16* yb)
{
  const int tid = threadIdx.x;
  const int d   = blockIdx.x*256 + tid;
  const int seg = blockIdx.y;
  const int b   = blockIdx.z;
  const int l0  = seg*SEG;

  __shared__ float BCs[SEG*32];
  {
    const float4* src = (const float4*)(bc + ((size_t)b*SEQL + l0)*32);
    float4* dst = (float4*)BCs;
    dst[tid]     = src[tid];
    dst[tid+256] = src[tid+256];
  }
  float As2[16];
  #pragma unroll
  for (int s=0;s<16;++s) As2[s] = -expf(A_log[s]) * LOG2E;
  float dcoef = Dp[d];
  __syncthreads();

  float h[16];
  #pragma unroll
  for (int s=0;s<16;++s) h[s]=0.f;

  const float* pp = Pq + ((size_t)b*NSEG)*32*1024 + d;
  for (int sg=0; sg<seg; ++sg) {
    const float* q = pp + (size_t)sg*32*1024;
    #pragma unroll
    for (int s=0;s<16;++s)
      h[s] = fmaf(h[s], q[(size_t)s*1024], q[(size_t)(16+s)*1024]);
  }

  size_t rbase = (size_t)b*SEQL + l0;
  const u16* pdt = dtb + rbase*DINNER + d;
  const u16* pu  = ub  + rbase*DINNER + d;
  const u16* pr  = xrb + rbase*2048 + 1024 + d;
  u16*       py  = yb  + rbase*DINNER + d;

  u16 dpf[8], upf[8], rpf[8];
  #pragma unroll
  for (int j=0;j<8;++j){
    dpf[j]=pdt[(size_t)j*DINNER]; upf[j]=pu[(size_t)j*DINNER]; rpf[j]=pr[(size_t)j*2048];
  }
  const u16* pdt_f = pdt + (size_t)8*DINNER;
  const u16* pu_f  = pu  + (size_t)8*DINNER;
  const u16* pr_f  = pr  + (size_t)8*2048;

  for (int l=0; l<SEG; l+=8) {
    bool pf = (l+8 < SEG);
    #pragma unroll
    for (int j=0;j<8;++j) {
      float dt = bf2f(dpf[j]), u = bf2f(upf[j]), rv = bf2f(rpf[j]);
      if (pf) { dpf[j] = *pdt_f; upf[j] = *pu_f; rpf[j] = *pr_f; }
      pdt_f += DINNER; pu_f += DINNER; pr_f += 2048;
      float dtu = dt*u;
      float acc = 0.f;
      const float* Bs = &BCs[(l+j)*32];
      #pragma unroll
      for (int s=0;s<16;++s) {
        float dA = exp2_fast(dt*As2[s]);
        h[s] = fmaf(h[s], dA, dtu*Bs[s]);
        acc  = fmaf(h[s], Bs[16+s], acc);
      }
      float y = fmaf(u, dcoef, acc);
      y *= rv * rcp_fast(1.f + exp2_fast(rv*(-LOG2E)));
      *py = f2bf(y);
      py += DINNER;
    }
  }
}

extern "C" void kernel_launch(void* const* d_in, const int* in_sizes, int n_in,
                              void* d_out, int out_size, void* d_ws, size_t ws_size,
                              hipStream_t stream)
{
  const float* x          = (const float*)d_in[0];
  const float* in_proj_w  = (const float*)d_in[1];
  const float* conv_w     = (const float*)d_in[2];
  const float* conv_b     = (const float*)d_in[3];
  const float* x_proj_w   = (const float*)d_in[4];
  const float* dt_proj_w  = (const float*)d_in[5];
  const float* dt_proj_b  = (const float*)d_in[6];
  const float* A_log      = (const float*)d_in[7];
  const float* Dvec       = (const float*)d_in[8];
  const float* out_proj_w = (const float*)d_in[9];
  const float* wq_w = (const float*)d_in[10]; const float* wq_b = (const float*)d_in[11];
  const float* wk_w = (const float*)d_in[12]; const float* wk_b = (const float*)d_in[13];
  const float* wv_w = (const float*)d_in[14]; const float* wv_b = (const float*)d_in[15];
  const float* wo_w = (const float*)d_in[16]; const float* wo_b = (const float*)d_in[17];
  const float* attn_ln_g = (const float*)d_in[18]; const float* attn_ln_b = (const float*)d_in[19];
  const float* ffn_w1 = (const float*)d_in[20]; const float* ffn_b1 = (const float*)d_in[21];
  const float* ffn_w2 = (const float*)d_in[22]; const float* ffn_b2 = (const float*)d_in[23];
  const float* norm1_g = (const float*)d_in[24]; const float* norm1_b = (const float*)d_in[25];
  const float* norm2_g = (const float*)d_in[26]; const float* norm2_b = (const float*)d_in[27];
  const float* norm3_g = (const float*)d_in[28]; const float* norm3_b = (const float*)d_in[29];
  const float* gate_w  = (const float*)d_in[30]; const float* gate_b  = (const float*)d_in[31];

  // ---- workspace layout ----
  float* ws  = (float*)d_ws;
  float* BC   = ws;                 // 262144 f32
  float* X1   = BC  + 262144;       // 4194304 f32 (x1 -> x3)
  float* XN2  = X1  + 4194304;      // 4194304 f32
  float* Pq   = XN2 + 4194304;      // 4194304 f32  [8][16][32][1024]
  u16* WT0 = (u16*)(Pq + 4194304);  // 6324224 u16 transposed weights
  u16* XRb = WT0 + 6324224;         // 16777216 u16 (xr); reused Q|K|VT|Hb; then FH
  u16* NB  = XRb + 16777216;        // 4194304 u16 (xn1b -> xn2b -> xn3b)
  u16* XCb = NB  + 4194304;         // 8388608 u16 (xc); reused MBb|ATTb
  u16* DTb = XCb + 8388608;         // 8388608 u16 (delta); reused WOUTb
  u16* Yb  = DTb + 8388608;         // 8388608 u16 (scan y)
  float* QKVB = (float*)(Yb + 8388608); // 1536 f32

  u16* Qb   = XRb;
  u16* Kb   = XRb + 4194304;
  u16* VTb  = XRb + 8388608;
  u16* Hbb  = XRb + 12582912;
  u16* FHb  = XRb;
  u16* MBb  = XCb;
  u16* ATTb = XCb + 4194304;
  u16* WOUTb= DTb;

  u16* inprojT = WT0;               // [2048,512]
  u16* xprojT  = inprojT + 1048576; // [32,1024]   (stacked with dtT -> 1056 rows)
  u16* dtT     = xprojT  + 32768;   // [1024,1024]
  u16* outT    = dtT     + 1048576; // [512,1024]
  u16* wqT     = outT    + 524288;  // [512,512]   (wq|wk|wv stacked -> 1536 rows)
  u16* wkT     = wqT     + 262144;
  u16* wvT     = wkT     + 262144;
  u16* woT     = wvT     + 262144;
  u16* ffn1T   = woT     + 262144;  // [2048,512]
  u16* ffn2T   = ffn1T   + 1048576; // [512,2048]
  u16* gateT   = ffn2T   + 1048576; // [512,1024]

  float* XOUT = (float*)d_out;
  float* AW   = (float*)d_out + 4194304;

  const float* nulf = nullptr;
  u16* nulh = nullptr;

  // 0) transpose + cvt weights; pack qkv bias
  WtArgs wa;
  wa.d[0]  = { in_proj_w, inprojT, 512, 2048, 0 };
  wa.d[1]  = { x_proj_w,  xprojT, 1024,   32, 256 };
  wa.d[2]  = { dt_proj_w, dtT,    1024, 1024, 272 };
  wa.d[3]  = { out_proj_w,outT,   1024,  512, 528 };
  wa.d[4]  = { wq_w,      wqT,     512,  512, 656 };
  wa.d[5]  = { wk_w,      wkT,     512,  512, 720 };
  wa.d[6]  = { wv_w,      wvT,     512,  512, 784 };
  wa.d[7]  = { wo_w,      woT,     512,  512, 848 };
  wa.d[8]  = { ffn_w1,    ffn1T,   512, 2048, 912 };
  wa.d[9]  = { ffn_w2,    ffn2T,  2048,  512, 1168 };
  wa.d[10] = { gate_w,    gateT,  1024,  512, 1424 };
  wt_k<<<1552, 256, 0, stream>>>(wa);
  pack3_k<<<6, 256, 0, stream>>>(wq_b, wk_b, wv_b, QKVB);

  // 1) xn1b = LN(x)
  ln_k<0><<<2048, 256, 0, stream>>>(x, nullptr, nullptr, norm1_g, norm1_b, nullptr, NB);
  // 2) xrb = xn1 @ in_proj (bf16)
  mm_k<7,0,128,128><<<dim3(16,64), 256, 0, stream>>>(NB,512, inprojT,512, XRb,2048,
        NROWS,2048,512, nulf,nulf,nulf,nulf,nulh,nulh);
  // 3) xc = silu(conv(xm)+cb) (bf16)
  conv_k<<<NROWS, 256, 0, stream>>>(XRb, conv_w, conv_b, XCb);
  // 4+5) BC (f32) | delta (bf16) fused: N=1056 over stacked [xprojT|dtT]
  mm_k<12,0,128,128><<<dim3(9,64), 256, 0, stream>>>(XCb,1024, xprojT,1024, BC,32,
        NROWS,1056,1024, dt_proj_b,nulf,nulf,nulf,nulh,DTb);
  // 6) chunked scan
  scan1_k<<<dim3(4,NSEG-1,8), 256, 0, stream>>>(DTb, XCb, BC, A_log, Pq);
  scan2_k<<<dim3(4,NSEG,8),   256, 0, stream>>>(DTb, XCb, BC, XRb, A_log, Dvec, Pq, Yb);
  // 7) mamba_out = y @ out_proj (bf16 only)  [64x64 tiles -> 1024 blocks]
  mm_k<7,0,64,64><<<dim3(8,128), 256, 0, stream>>>(Yb,1024, outT,1024, MBb,512,
        NROWS,512,1024, nulf,nulf,nulf,nulf,nulh,nulh);
  // 8) x1 = x + mamba_out(bf16) ; xn2 = LN(x1)
  ln_k<1><<<2048, 256, 0, stream>>>(x, MBb, X1, norm2_g, norm2_b, XN2, NB);
  // 9) QKV fused: N=1536 over stacked [wqT|wkT|wvT]
  mm_k<11,0,128,128><<<dim3(12,64), 256, 0, stream>>>(NB,512, wqT,512, Qb,512,
        NROWS,1536,512, QKVB,nulf,nulf,nulf,nulh,VTb);
  // 10-12) fused attention (16-row q-tiles, two k-halves): AW (d_out) + Hbb
  attn_k<<<dim3(64,64), 256, 0, stream>>>(Qb, Kb, VTb, AW, Hbb);
  // 13) wo_out = Hb @ wo + b (bf16)  [64x64]
  mm_k<8,0,64,64><<<dim3(8,128), 256, 0, stream>>>(Hbb,512, woT,512, WOUTb,512,
        NROWS,512,512, wo_b,nulf,nulf,nulf,nulh,nulh);
  // 14) attn_out = LN(wo_out(bf16) + xn2(f32)) -> bf16 only
  ln_k<2><<<2048, 256, 0, stream>>>(WOUTb, XN2, nullptr, attn_ln_g, attn_ln_b, nullptr, ATTb);
  // 15) gate fusion -> X1 (x3 in place)  [64x64, bf16 m/at]
  mm_k<6,3,64,64><<<dim3(8,128), 256, 0, stream>>>(MBb,512, gateT,1024, X1,512,
        NROWS,512,1024, gate_b, (const float*)MBb, (const float*)ATTb, X1, ATTb, nulh);
  // 16) xn3b = LN(x3)
  ln_k<0><<<2048, 256, 0, stream>>>(X1, nullptr, nullptr, norm3_g, norm3_b, nullptr, NB);
  // 17) fh = gelu(xn3 @ ffn1 + b1) (bf16)
  mm_k<3,0,128,128><<<dim3(16,64), 256, 0, stream>>>(NB,512, ffn1T,512, FHb,2048,
        NROWS,2048,512, ffn_b1,nulf,nulf,nulf,nulh,nulh);
  // 18) out = x3 + fh @ ffn2 + b2 -> d_out  [64x64]
  mm_k<5,0,64,64><<<dim3(8,128), 256, 0, stream>>>(FHb,2048, ffn2T,2048, XOUT,512,
        NROWS,512,2048, ffn_b2, X1,nulf,nulf,nulh,nulh);
}

// Round 12
// 547.249 us; speedup vs baseline: 1.1579x; 1.1579x over previous
//
#include <hip/hip_runtime.h>

#define SEQL 1024
#define DMODEL 512
#define DINNER 1024
#define NROWS 8192
#define SEG 64
#define NSEG 16
#define LOG2E 1.4426950408889634f

typedef unsigned short u16;
typedef unsigned int u32;
using bf16x8 = __attribute__((ext_vector_type(8))) short;
using f32x4  = __attribute__((ext_vector_type(4))) float;
using u16x4  = __attribute__((ext_vector_type(4))) unsigned short;
using u16x8  = __attribute__((ext_vector_type(8))) unsigned short;

__device__ __forceinline__ float rcp_fast(float x){ return __builtin_amdgcn_rcpf(x); }
__device__ __forceinline__ float exp_fast(float x){ return __expf(x); }
#if __has_builtin(__builtin_amdgcn_exp2f)
__device__ __forceinline__ float exp2_fast(float x){ return __builtin_amdgcn_exp2f(x); }
#else
__device__ __forceinline__ float exp2_fast(float x){ return __expf(x*0.6931471805599453f); }
#endif
__device__ __forceinline__ float sigmoid_f(float x){ return rcp_fast(1.f+exp_fast(-x)); }
__device__ __forceinline__ float softplus_f(float x){ return fmaxf(x,0.f)+__logf(1.f+exp_fast(-fabsf(x))); }
__device__ __forceinline__ float gelu_f(float x){
  float u2 = 1.5957691216057308f*(x+0.044715f*x*x*x);
  float t = 1.f - 2.f*rcp_fast(1.f+exp_fast(u2));
  return 0.5f*x*(1.f+t);
}
__device__ __forceinline__ u16 f2bf(float f){
  u32 u = __builtin_bit_cast(u32, f);
  return (u16)((u + 0x7FFFu + ((u>>16)&1u)) >> 16);
}
__device__ __forceinline__ float bf2f(u16 h){
  return __builtin_bit_cast(float, (u32)h << 16);
}

// async global -> LDS, 16B per lane (LDS dest must be linear in lane order)
typedef __attribute__((address_space(1))) const void g_void;
typedef __attribute__((address_space(3))) void l_void;
__device__ __forceinline__ void gl_lds16(const void* g, void* l){
  __builtin_amdgcn_global_load_lds((g_void*)g, (l_void*)l, 16, 0, 0);
}

// ---------------- weight transpose+cvt: [K,N] fp32 -> [N,K] bf16 ---------------
struct WtDesc { const float* src; u16* dst; int K; int N; int t0; };
struct WtArgs { WtDesc d[11]; };

__global__ __launch_bounds__(256) void wt_k(WtArgs a)
{
  __shared__ float t[64][65];
  int bid = blockIdx.x;
  int i = 0;
  #pragma unroll
  for (int j=1;j<11;++j) if (bid >= a.d[j].t0) i = j;
  const float* src = a.d[i].src; u16* dst = a.d[i].dst;
  int K = a.d[i].K, N = a.d[i].N;
  int ntN = (N+63)>>6;
  int loc = bid - a.d[i].t0;
  int k0 = (loc / ntN)*64, n0 = (loc % ntN)*64;
  int tr = threadIdx.x>>4, tc = threadIdx.x&15;
  #pragma unroll
  for (int p=0;p<4;++p) {
    int r = p*16 + tr; int c = tc*4;
    if (n0 + c < N) {
      float4 v = *(const float4*)(src + (size_t)(k0+r)*N + n0 + c);
      t[r][c]=v.x; t[r][c+1]=v.y; t[r][c+2]=v.z; t[r][c+3]=v.w;
    }
  }
  __syncthreads();
  #pragma unroll
  for (int p=0;p<4;++p) {
    int n = p*16 + tr; int k = tc*4;
    if (n0 + n < N) {
      u16x4 o = { f2bf(t[k][n]), f2bf(t[k+1][n]), f2bf(t[k+2][n]), f2bf(t[k+3][n]) };
      *(u16x4*)(dst + (size_t)(n0+n)*K + k0 + k) = o;
    }
  }
}

// ---------------- bias concat for QKV -----------------------------------------
__global__ __launch_bounds__(256) void pack3_k(const float* a, const float* b,
                                               const float* c, float* o)
{
  int t = blockIdx.x*256 + threadIdx.x;
  if (t < 512) o[t] = a[t];
  else if (t < 1024) o[t] = b[t-512];
  else if (t < 1536) o[t] = c[t-1024];
}

// ---------------- LayerNorm (D=512): one wave per row, no barriers -------------
// AM: 0 = a f32, no b ; 1 = a f32 + b bf16 ; 2 = a bf16 + b f32
template<int AM>
__global__ __launch_bounds__(256) void ln_k(const void* av, const void* bv, float* resid,
                                            const float* g, const float* beta,
                                            float* outf, u16* outb)
{
  const int lane = threadIdx.x & 63;
  const int row = (blockIdx.x<<2) + (threadIdx.x>>6);
  size_t off = (size_t)row*DMODEL + lane*8;
  float v[8];
  if (AM==2) {
    u16x8 va = *(const u16x8*)((const u16*)av + off);
    #pragma unroll
    for (int i=0;i<8;++i) v[i] = bf2f(va[i]);
  } else {
    float4 a0 = *(const float4*)((const float*)av + off);
    float4 a1 = *(const float4*)((const float*)av + off + 4);
    v[0]=a0.x; v[1]=a0.y; v[2]=a0.z; v[3]=a0.w;
    v[4]=a1.x; v[5]=a1.y; v[6]=a1.z; v[7]=a1.w;
  }
  if (AM==1) {
    u16x8 wb = *(const u16x8*)((const u16*)bv + off);
    #pragma unroll
    for (int i=0;i<8;++i) v[i] += bf2f(wb[i]);
  } else if (AM==2) {
    float4 b0 = *(const float4*)((const float*)bv + off);
    float4 b1 = *(const float4*)((const float*)bv + off + 4);
    v[0]+=b0.x; v[1]+=b0.y; v[2]+=b0.z; v[3]+=b0.w;
    v[4]+=b1.x; v[5]+=b1.y; v[6]+=b1.z; v[7]+=b1.w;
  }
  if (resid) {
    float4 r0 = {v[0],v[1],v[2],v[3]};
    float4 r1 = {v[4],v[5],v[6],v[7]};
    *(float4*)(resid + off) = r0;
    *(float4*)(resid + off + 4) = r1;
  }
  float s=0.f, q=0.f;
  #pragma unroll
  for (int i=0;i<8;++i){ s += v[i]; q = fmaf(v[i], v[i], q); }
  #pragma unroll
  for (int o=1;o<64;o<<=1){ s += __shfl_xor(s,o); q += __shfl_xor(q,o); }
  float mean = s*(1.f/512.f);
  float var  = q*(1.f/512.f) - mean*mean;
  float rstd = rsqrtf(var + 1e-5f);
  int c = lane*8;
  float4 g0 = *(const float4*)(g+c);
  float4 g1 = *(const float4*)(g+c+4);
  float4 b0 = *(const float4*)(beta+c);
  float4 b1 = *(const float4*)(beta+c+4);
  float gg[8] = {g0.x,g0.y,g0.z,g0.w,g1.x,g1.y,g1.z,g1.w};
  float bb[8] = {b0.x,b0.y,b0.z,b0.w,b1.x,b1.y,b1.z,b1.w};
  float o8[8];
  #pragma unroll
  for (int i=0;i<8;++i) o8[i] = (v[i]-mean)*rstd*gg[i] + bb[i];
  if (outf) {
    float4 f0 = {o8[0],o8[1],o8[2],o8[3]};
    float4 f1 = {o8[4],o8[5],o8[6],o8[7]};
    *(float4*)(outf + off) = f0;
    *(float4*)(outf + off + 4) = f1;
  }
  if (outb) {
    u16x8 ob = { f2bf(o8[0]),f2bf(o8[1]),f2bf(o8[2]),f2bf(o8[3]),
                 f2bf(o8[4]),f2bf(o8[5]),f2bf(o8[6]),f2bf(o8[7]) };
    *(u16x8*)(outb + off) = ob;
  }
}

// ---------------- bf16 MFMA GEMM, TMxTN tile, BK=32, dbuf LDS, 1 barrier/step --
// EPI: 3 gelu(x+bias) bf16, 5 x+bias+p0 f32, 6 gate fusion (bf16 p0/p1, f32 p2) f32,
//      7 bf16, 8 bf16+bias,
//      11 QKV fused (cols 0-1023 -> Q/K bf16 + bias; 1024-1535 -> V transposed to aux),
//      12 BC|delta fused (cols 0-31 -> Cf raw f32; 32-1055 -> softplus+bias -> bf16 aux)
// BMODE: 0 plain, 3 stitched A|A2 (K=1024)
// TM/TN: 128 or 64 (waves 2x2; per-wave sub-tile TM/2 x TN/2)
template<int EPI, int BMODE, int TM, int TN>
__global__ __launch_bounds__(256) void mm_k(
    const u16* Ab, int lda, const u16* Bb, int ldb,
    void* Cv, int ldc, int M, int N, int K,
    const float* bias, const float* p0, const float* p1, const float* p2,
    const u16* A2b, u16* aux)
{
  constexpr int NI = TM/32;
  constexpr int NJ = TN/32;
  __shared__ u16 As[2][TM][32];
  __shared__ u16 Bs[2][TN][32];
  const int tid = threadIdx.x;
  const int bx = blockIdx.x, by = blockIdx.y;
  float* Cf = (float*)Cv;
  u16* Cb = (u16*)Cv;
  const int row0 = by*TM, col0 = bx*TN;
  const int sr = tid>>2, sc = tid&3;
  const int wv = tid>>6, lane = tid&63;
  const int wr = wv>>1, wc = wv&1;
  const int lr = lane&15, lk = (lane>>4)*8;
  const int lq = lane>>4;

  f32x4 acc[NI][NJ];
  #pragma unroll
  for (int i=0;i<NI;++i)
    #pragma unroll
    for (int j=0;j<NJ;++j)
      acc[i][j] = (f32x4){0.f,0.f,0.f,0.f};

  auto stage = [&](int buf, int k0){
    #pragma unroll
    for (int h=0; h<TM/64; ++h) {
      int row = sr + h*64;
      const u16* src;
      if (BMODE==3) {
        int kk = k0 + sc*8;
        src = (kk < 512) ? Ab + (size_t)(row0+row)*512 + kk
                         : A2b + (size_t)(row0+row)*512 + (kk-512);
      } else {
        src = Ab + (size_t)(row0+row)*lda + k0 + sc*8;
      }
      gl_lds16(src, &As[buf][row][sc*8]);
    }
    #pragma unroll
    for (int h=0; h<TN/64; ++h) {
      int rowb = sr + h*64;
      gl_lds16(Bb + (size_t)(col0+rowb)*ldb + k0 + sc*8, &Bs[buf][rowb][sc*8]);
    }
  };

  const int nt = K/32;
  stage(0, 0);
  __syncthreads();
  for (int t=0; t<nt; ++t) {
    int buf = t&1;
    if (t+1 < nt) stage(buf^1, (t+1)*32);
    bf16x8 fa[NI], fb[NJ];
    #pragma unroll
    for (int i=0;i<NI;++i) fa[i] = *(const bf16x8*)&As[buf][wr*(TM/2) + i*16 + lr][lk];
    #pragma unroll
    for (int j=0;j<NJ;++j) fb[j] = *(const bf16x8*)&Bs[buf][wc*(TN/2) + j*16 + lr][lk];
    #pragma unroll
    for (int i=0;i<NI;++i)
      #pragma unroll
      for (int j=0;j<NJ;++j)
        acc[i][j] = __builtin_amdgcn_mfma_f32_16x16x32_bf16(fa[i], fb[j], acc[i][j], 0,0,0);
    __syncthreads();
  }

  #pragma unroll
  for (int i=0;i<NI;++i) {
    #pragma unroll
    for (int j=0;j<NJ;++j) {
      int col = col0 + wc*(TN/2) + j*16 + lr;
      if (col >= N) continue;
      int rowbase = row0 + wr*(TM/2) + i*16 + lq*4;
      f32x4 v4 = acc[i][j];
      if (EPI==11 && col >= 1024) {
        int c2 = col-1024;
        int b2 = rowbase >> 10;
        int l2 = rowbase & 1023;
        float bv = bias[col];
        u16x4 pk = { f2bf(v4[0]+bv), f2bf(v4[1]+bv), f2bf(v4[2]+bv), f2bf(v4[3]+bv) };
        *(u16x4*)(aux + (size_t)b2*DMODEL*SEQL + (size_t)c2*SEQL + l2) = pk;
        continue;
      }
      #pragma unroll
      for (int r=0;r<4;++r) {
        int row = rowbase + r;
        size_t idx = (size_t)row*ldc + col;
        float v = v4[r];
        if (EPI==3) Cb[idx] = f2bf(gelu_f(v + bias[col]));
        else if (EPI==5) Cf[idx] = v + bias[col] + p0[idx];
        else if (EPI==6) {
          float g = sigmoid_f(v + bias[col]);
          float m  = bf2f(((const u16*)p0)[idx]);
          float at = bf2f(((const u16*)p1)[idx]);
          Cf[idx] = p2[idx] + at + g*m + (1.f-g)*at;
        }
        else if (EPI==7) Cb[idx] = f2bf(v);
        else if (EPI==8) Cb[idx] = f2bf(v + bias[col]);
        else if (EPI==11) {
          size_t i2 = (size_t)(col>>9)*4194304 + (size_t)row*512 + (col&511);
          Cb[i2] = f2bf(v + bias[col]);
        }
        else if (EPI==12) {
          if (col < 32) Cf[(size_t)row*32 + col] = v;
          else aux[(size_t)row*1024 + (col-32)] = f2bf(softplus_f(v + bias[col-32]));
        }
      }
    }
  }
}

// ---------------- fused attention: 16-row q-tiles, single-pass PV --------------
// grid (qt=64, bh=64), 256 thr (4 waves). Scores: wave w covers k-cols w*256..+256.
// Single full-width Ps (36 KB LDS, 4 barriers). AW written nontemporal from regs
// (drains under PV). PV: n-split, wave w owns d-cols w*16..+16, full K range.
__global__ __launch_bounds__(256) void attn_k(const u16* Qb, const u16* Kb,
                                              const u16* VTb, float* AW, u16* Hbb)
{
  __shared__ u16 Qs[16][72];
  __shared__ u16 Ps[16][1032];
  __shared__ float smax[4][16];
  __shared__ float ssum[4][16];

  const int tid = threadIdx.x;
  const int w = tid>>6, lane = tid&63;
  const int qt = blockIdx.x, bh = blockIdx.y;
  const int b = bh>>3, h = bh&7;
  const int q0 = qt*16;
  const int lr = lane&15, lg = lane>>4;
  const int rw = lg*4;

  {
    int r = tid>>4, c = (tid&15)*4;
    const u16* src = Qb + ((size_t)(b*1024 + q0 + r))*512 + h*64 + c;
    *(u16x4*)&Qs[r][c] = *(const u16x4*)src;
  }
  __syncthreads();

  f32x4 acc[16];
  #pragma unroll
  for (int j=0;j<16;++j) acc[j] = (f32x4){0.f,0.f,0.f,0.f};
  bf16x8 fa0 = *(const bf16x8*)&Qs[lr][lg*8];
  bf16x8 fa1 = *(const bf16x8*)&Qs[lr][32+lg*8];
  const u16* Kbase = Kb + ((size_t)(b*1024 + w*256))*512 + h*64;
  __builtin_amdgcn_s_setprio(1);
  #pragma unroll
  for (int j=0;j<16;++j){
    const u16* krow = Kbase + (size_t)(j*16 + lr)*512 + lg*8;
    bf16x8 fb0 = *(const bf16x8*)krow;
    bf16x8 fb1 = *(const bf16x8*)(krow+32);
    acc[j] = __builtin_amdgcn_mfma_f32_16x16x32_bf16(fa0, fb0, acc[j], 0,0,0);
    acc[j] = __builtin_amdgcn_mfma_f32_16x16x32_bf16(fa1, fb1, acc[j], 0,0,0);
  }
  __builtin_amdgcn_s_setprio(0);

  float mg[4] = {-1e30f,-1e30f,-1e30f,-1e30f};
  #pragma unroll
  for (int j=0;j<16;++j)
    #pragma unroll
    for (int r=0;r<4;++r) mg[r]=fmaxf(mg[r],acc[j][r]);
  #pragma unroll
  for (int o=1;o<16;o<<=1)
    #pragma unroll
    for (int r=0;r<4;++r) mg[r]=fmaxf(mg[r],__shfl_xor(mg[r],o));
  if (lr==0){
    #pragma unroll
    for (int r=0;r<4;++r) smax[w][rw+r]=mg[r];
  }
  __syncthreads();
  #pragma unroll
  for (int r=0;r<4;++r)
    mg[r] = fmaxf(fmaxf(smax[0][rw+r],smax[1][rw+r]),fmaxf(smax[2][rw+r],smax[3][rw+r]));
  const float cs = 0.125f*LOG2E;
  float sg[4]={0.f,0.f,0.f,0.f};
  #pragma unroll
  for (int j=0;j<16;++j)
    #pragma unroll
    for (int r=0;r<4;++r){
      acc[j][r]=exp2_fast((acc[j][r]-mg[r])*cs); sg[r]+=acc[j][r];
    }
  #pragma unroll
  for (int o=1;o<16;o<<=1)
    #pragma unroll
    for (int r=0;r<4;++r) sg[r]+=__shfl_xor(sg[r],o);
  if (lr==0){
    #pragma unroll
    for (int r=0;r<4;++r) ssum[w][rw+r]=sg[r];
  }
  __syncthreads();
  float ig[4];
  #pragma unroll
  for (int r=0;r<4;++r)
    ig[r] = rcp_fast(ssum[0][rw+r]+ssum[1][rw+r]+ssum[2][rw+r]+ssum[3][rw+r]);

  // write normalized P: LDS (bf16) + AW nontemporal f32 from registers
  float* awr = AW + (size_t)bh*1048576 + (size_t)q0*1024 + (size_t)w*256;
  #pragma unroll
  for (int j=0;j<16;++j){
    int col = j*16 + lr;
    #pragma unroll
    for (int r=0;r<4;++r){
      float v = acc[j][r]*ig[r];
      Ps[rw+r][w*256+col] = f2bf(v);
      __builtin_nontemporal_store(v, awr + (size_t)(rw+r)*1024 + col);
    }
  }
  __syncthreads();

  // PV single pass: wave w owns d-cols w*16..+16, full k range
  f32x4 av = (f32x4){0.f,0.f,0.f,0.f};
  const u16* Vbase = VTb + (size_t)b*524288 + (size_t)(h*64 + w*16 + lr)*1024;
  __builtin_amdgcn_s_setprio(1);
  #pragma unroll
  for (int ks=0; ks<32; ++ks){
    bf16x8 fb  = *(const bf16x8*)(Vbase + ks*32 + lg*8);
    bf16x8 pa  = *(const bf16x8*)&Ps[lr][ks*32 + lg*8];
    av = __builtin_amdgcn_mfma_f32_16x16x32_bf16(pa, fb, av, 0,0,0);
  }
  __builtin_amdgcn_s_setprio(0);

  u16* ob = Hbb + ((size_t)(b*1024 + q0))*512 + h*64 + w*16 + lr;
  #pragma unroll
  for (int r=0;r<4;++r)
    ob[(size_t)(rw+r)*512] = f2bf(av[r]);
}

// ---------------- causal depthwise conv (D_CONV=4) + SiLU, bf16 in/out ---------
__global__ __launch_bounds__(256) void conv_k(const u16* xrb, const float* cw,
                                              const float* cb, u16* xcb)
{
  int t = blockIdx.x*256 + threadIdx.x;
  int d = (t & 255)*4;
  int row = t >> 8;
  int l = row & (SEQL-1);
  const u16* xmb = xrb + (size_t)(row - l)*2048 + d;
  float wv[4][4];
  #pragma unroll
  for (int dd=0; dd<4; ++dd){
    float4 w = *(const float4*)(cw + (size_t)(d+dd)*4);
    wv[dd][0]=w.x; wv[dd][1]=w.y; wv[dd][2]=w.z; wv[dd][3]=w.w;
  }
  float4 acc = *(const float4*)(cb + d);
  #pragma unroll
  for (int k=0;k<4;++k){
    int ls = l + k - 3;
    if (ls >= 0) {
      u16x4 xv = *(const u16x4*)(xmb + (size_t)ls*2048);
      acc.x += wv[0][k]*bf2f(xv[0]);
      acc.y += wv[1][k]*bf2f(xv[1]);
      acc.z += wv[2][k]*bf2f(xv[2]);
      acc.w += wv[3][k]*bf2f(xv[3]);
    }
  }
  float sx = acc.x*rcp_fast(1.f+exp_fast(-acc.x));
  float sy = acc.y*rcp_fast(1.f+exp_fast(-acc.y));
  float sz = acc.z*rcp_fast(1.f+exp_fast(-acc.z));
  float sw = acc.w*rcp_fast(1.f+exp_fast(-acc.w));
  size_t off = (size_t)row*DINNER + d;
  u16x4 ob = { f2bf(sx), f2bf(sy), f2bf(sz), f2bf(sw) };
  *(u16x4*)(xcb + off) = ob;
}

// ---------------- selective scan, chunked two-pass -----------------------------
__global__ __launch_bounds__(256) void scan1_k(const u16* dtb, const u16* ub,
                                               const float* bc, const float* A_log,
                                               float* Pq)
{
  const int tid = threadIdx.x;
  const int d   = blockIdx.x*256 + tid;
  const int seg = blockIdx.y;
  const int b   = blockIdx.z;
  const int l0  = seg*SEG;

  __shared__ float BCs[SEG*32];
  {
    const float4* src = (const float4*)(bc + ((size_t)b*SEQL + l0)*32);
    float4* dst = (float4*)BCs;
    dst[tid]     = src[tid];
    dst[tid+256] = src[tid+256];
  }
  float As2[16];
  #pragma unroll
  for (int s=0;s<16;++s) As2[s] = -expf(A_log[s]) * LOG2E;
  __syncthreads();

  float h[16], P[16];
  #pragma unroll
  for (int s=0;s<16;++s){ h[s]=0.f; P[s]=1.f; }

  size_t base = ((size_t)b*SEQL + l0)*DINNER + d;
  const u16* pdt = dtb + base;
  const u16* pu  = ub  + base;

  u16 dpf[8], upf[8];
  #pragma unroll
  for (int j=0;j<8;++j){ dpf[j]=pdt[(size_t)j*DINNER]; upf[j]=pu[(size_t)j*DINNER]; }
  const u16* pdt_f = pdt + (size_t)8*DINNER;
  const u16* pu_f  = pu  + (size_t)8*DINNER;

  for (int l=0; l<SEG; l+=8) {
    bool pf = (l+8 < SEG);
    #pragma unroll
    for (int j=0;j<8;++j) {
      float dt = bf2f(dpf[j]), u = bf2f(upf[j]);
      if (pf) { dpf[j] = *pdt_f; upf[j] = *pu_f; }
      pdt_f += DINNER; pu_f += DINNER;
      float dtu = dt*u;
      const float* Bs = &BCs[(l+j)*32];
      #pragma unroll
      for (int s=0;s<16;++s) {
        float dA = exp2_fast(dt*As2[s]);
        P[s] *= dA;
        h[s] = fmaf(h[s], dA, dtu*Bs[s]);
      }
    }
  }
  float* out = Pq + (((size_t)b*NSEG + seg)*32)*1024 + d;
  #pragma unroll
  for (int s=0;s<16;++s) {
    out[(size_t)s*1024]      = P[s];
    out[(size_t)(16+s)*1024] = h[s];
  }
}

__global__ __launch_bounds__(256) void scan2_k(const u16* dtb, const u16* ub,
                                               const float* bc, const u16* xrb,
                                               const float* A_log, const float* Dp,
                                               const float* Pq, u16* yb)
{
  const int tid = threadIdx.x;
  const int d   = blockIdx.x*256 + tid;
  const int seg = blockIdx.y;
  const int b   = blockIdx.z;
  const int l0  = seg*SEG;

  __shared__ float BCs[SEG*32];
  {
    const float4* src = (const float4*)(bc + ((size_t)b*SEQL + l0)*32);
    float4* dst = (float4*)BCs;
    dst[tid]     = src[tid];
    dst[tid+256] = src[tid+256];
  }
  float As2[16];
  #pragma unroll
  for (int s=0;s<16;++s) As2[s] = -expf(A_log[s]) * LOG2E;
  float dcoef = Dp[d];
  __syncthreads();

  float h[16];
  #pragma unroll
  for (int s=0;s<16;++s) h[s]=0.f;

  const float* pp = Pq + ((size_t)b*NSEG)*32*1024 + d;
  for (int sg=0; sg<seg; ++sg) {
    const float* q = pp + (size_t)sg*32*1024;
    #pragma unroll
    for (int s=0;s<16;++s)
      h[s] = fmaf(h[s], q[(size_t)s*1024], q[(size_t)(16+s)*1024]);
  }

  size_t rbase = (size_t)b*SEQL + l0;
  const u16* pdt = dtb + rbase*DINNER + d;
  const u16* pu  = ub  + rbase*DINNER + d;
  const u16* pr  = xrb + rbase*2048 + 1024 + d;
  u16*       py  = yb  + rbase*DINNER + d;

  u16 dpf[8], upf[8], rpf[8];
  #pragma unroll
  for (int j=0;j<8;++j){
    dpf[j]=pdt[(size_t)j*DINNER]; upf[j]=pu[(size_t)j*DINNER]; rpf[j]=pr[(size_t)j*2048];
  }
  const u16* pdt_f = pdt + (size_t)8*DINNER;
  const u16* pu_f  = pu  + (size_t)8*DINNER;
  const u16* pr_f  = pr  + (size_t)8*2048;

  for (int l=0; l<SEG; l+=8) {
    bool pf = (l+8 < SEG);
    #pragma unroll
    for (int j=0;j<8;++j) {
      float dt = bf2f(dpf[j]), u = bf2f(upf[j]), rv = bf2f(rpf[j]);
      if (pf) { dpf[j] = *pdt_f; upf[j] = *pu_f; rpf[j] = *pr_f; }
      pdt_f += DINNER; pu_f += DINNER; pr_f += 2048;
      float dtu = dt*u;
      float acc = 0.f;
      const float* Bs = &BCs[(l+j)*32];
      #pragma unroll
      for (int s=0;s<16;++s) {
        float dA = exp2_fast(dt*As2[s]);
        h[s] = fmaf(h[s], dA, dtu*Bs[s]);
        acc  = fmaf(h[s], Bs[16+s], acc);
      }
      float y = fmaf(u, dcoef, acc);
      y *= rv * rcp_fast(1.f + exp2_fast(rv*(-LOG2E)));
      *py = f2bf(y);
      py += DINNER;
    }
  }
}

extern "C" void kernel_launch(void* const* d_in, const int* in_sizes, int n_in,
                              void* d_out, int out_size, void* d_ws, size_t ws_size,
                              hipStream_t stream)
{
  const float* x          = (const float*)d_in[0];
  const float* in_proj_w  = (const float*)d_in[1];
  const float* conv_w     = (const float*)d_in[2];
  const float* conv_b     = (const float*)d_in[3];
  const float* x_proj_w   = (const float*)d_in[4];
  const float* dt_proj_w  = (const float*)d_in[5];
  const float* dt_proj_b  = (const float*)d_in[6];
  const float* A_log      = (const float*)d_in[7];
  const float* Dvec       = (const float*)d_in[8];
  const float* out_proj_w = (const float*)d_in[9];
  const float* wq_w = (const float*)d_in[10]; const float* wq_b = (const float*)d_in[11];
  const float* wk_w = (const float*)d_in[12]; const float* wk_b = (const float*)d_in[13];
  const float* wv_w = (const float*)d_in[14]; const float* wv_b = (const float*)d_in[15];
  const float* wo_w = (const float*)d_in[16]; const float* wo_b = (const float*)d_in[17];
  const float* attn_ln_g = (const float*)d_in[18]; const float* attn_ln_b = (const float*)d_in[19];
  const float* ffn_w1 = (const float*)d_in[20]; const float* ffn_b1 = (const float*)d_in[21];
  const float* ffn_w2 = (const float*)d_in[22]; const float* ffn_b2 = (const float*)d_in[23];
  const float* norm1_g = (const float*)d_in[24]; const float* norm1_b = (const float*)d_in[25];
  const float* norm2_g = (const float*)d_in[26]; const float* norm2_b = (const float*)d_in[27];
  const float* norm3_g = (const float*)d_in[28]; const float* norm3_b = (const float*)d_in[29];
  const float* gate_w  = (const float*)d_in[30]; const float* gate_b  = (const float*)d_in[31];

  // ---- workspace layout ----
  float* ws  = (float*)d_ws;
  float* BC   = ws;                 // 262144 f32
  float* X1   = BC  + 262144;       // 4194304 f32 (x1 -> x3)
  float* XN2  = X1  + 4194304;      // 4194304 f32
  float* Pq   = XN2 + 4194304;      // 4194304 f32  [8][16][32][1024]
  u16* WT0 = (u16*)(Pq + 4194304);  // 6324224 u16 transposed weights
  u16* XRb = WT0 + 6324224;         // 16777216 u16 (xr); reused Q|K|VT|Hb; then FH
  u16* NB  = XRb + 16777216;        // 4194304 u16 (xn1b -> xn2b -> xn3b)
  u16* XCb = NB  + 4194304;         // 8388608 u16 (xc); reused MBb|ATTb
  u16* DTb = XCb + 8388608;         // 8388608 u16 (delta); reused WOUTb
  u16* Yb  = DTb + 8388608;         // 8388608 u16 (scan y)
  float* QKVB = (float*)(Yb + 8388608); // 1536 f32

  u16* Qb   = XRb;
  u16* Kb   = XRb + 4194304;
  u16* VTb  = XRb + 8388608;
  u16* Hbb  = XRb + 12582912;
  u16* FHb  = XRb;
  u16* MBb  = XCb;
  u16* ATTb = XCb + 4194304;
  u16* WOUTb= DTb;

  u16* inprojT = WT0;               // [2048,512]
  u16* xprojT  = inprojT + 1048576; // [32,1024]   (stacked with dtT -> 1056 rows)
  u16* dtT     = xprojT  + 32768;   // [1024,1024]
  u16* outT    = dtT     + 1048576; // [512,1024]
  u16* wqT     = outT    + 524288;  // [512,512]   (wq|wk|wv stacked -> 1536 rows)
  u16* wkT     = wqT     + 262144;
  u16* wvT     = wkT     + 262144;
  u16* woT     = wvT     + 262144;
  u16* ffn1T   = woT     + 262144;  // [2048,512]
  u16* ffn2T   = ffn1T   + 1048576; // [512,2048]
  u16* gateT   = ffn2T   + 1048576; // [512,1024]

  float* XOUT = (float*)d_out;
  float* AW   = (float*)d_out + 4194304;

  const float* nulf = nullptr;
  u16* nulh = nullptr;

  // 0) transpose + cvt weights; pack qkv bias
  WtArgs wa;
  wa.d[0]  = { in_proj_w, inprojT, 512, 2048, 0 };
  wa.d[1]  = { x_proj_w,  xprojT, 1024,   32, 256 };
  wa.d[2]  = { dt_proj_w, dtT,    1024, 1024, 272 };
  wa.d[3]  = { out_proj_w,outT,   1024,  512, 528 };
  wa.d[4]  = { wq_w,      wqT,     512,  512, 656 };
  wa.d[5]  = { wk_w,      wkT,     512,  512, 720 };
  wa.d[6]  = { wv_w,      wvT,     512,  512, 784 };
  wa.d[7]  = { wo_w,      woT,     512,  512, 848 };
  wa.d[8]  = { ffn_w1,    ffn1T,   512, 2048, 912 };
  wa.d[9]  = { ffn_w2,    ffn2T,  2048,  512, 1168 };
  wa.d[10] = { gate_w,    gateT,  1024,  512, 1424 };
  wt_k<<<1552, 256, 0, stream>>>(wa);
  pack3_k<<<6, 256, 0, stream>>>(wq_b, wk_b, wv_b, QKVB);

  // 1) xn1b = LN(x)
  ln_k<0><<<2048, 256, 0, stream>>>(x, nullptr, nullptr, norm1_g, norm1_b, nullptr, NB);
  // 2) xrb = xn1 @ in_proj (bf16)
  mm_k<7,0,128,128><<<dim3(16,64), 256, 0, stream>>>(NB,512, inprojT,512, XRb,2048,
        NROWS,2048,512, nulf,nulf,nulf,nulf,nulh,nulh);
  // 3) xc = silu(conv(xm)+cb) (bf16)
  conv_k<<<NROWS, 256, 0, stream>>>(XRb, conv_w, conv_b, XCb);
  // 4+5) BC (f32) | delta (bf16) fused: N=1056 over stacked [xprojT|dtT]
  mm_k<12,0,128,128><<<dim3(9,64), 256, 0, stream>>>(XCb,1024, xprojT,1024, BC,32,
        NROWS,1056,1024, dt_proj_b,nulf,nulf,nulf,nulh,DTb);
  // 6) chunked scan
  scan1_k<<<dim3(4,NSEG-1,8), 256, 0, stream>>>(DTb, XCb, BC, A_log, Pq);
  scan2_k<<<dim3(4,NSEG,8),   256, 0, stream>>>(DTb, XCb, BC, XRb, A_log, Dvec, Pq, Yb);
  // 7) mamba_out = y @ out_proj (bf16 only)  [64x64 tiles -> 1024 blocks]
  mm_k<7,0,64,64><<<dim3(8,128), 256, 0, stream>>>(Yb,1024, outT,1024, MBb,512,
        NROWS,512,1024, nulf,nulf,nulf,nulf,nulh,nulh);
  // 8) x1 = x + mamba_out(bf16) ; xn2 = LN(x1)
  ln_k<1><<<2048, 256, 0, stream>>>(x, MBb, X1, norm2_g, norm2_b, XN2, NB);
  // 9) QKV fused: N=1536 over stacked [wqT|wkT|wvT]
  mm_k<11,0,128,128><<<dim3(12,64), 256, 0, stream>>>(NB,512, wqT,512, Qb,512,
        NROWS,1536,512, QKVB,nulf,nulf,nulf,nulh,VTb);
  // 10-12) fused attention (16-row q-tiles, single PV pass): AW (d_out, NT) + Hbb
  attn_k<<<dim3(64,64), 256, 0, stream>>>(Qb, Kb, VTb, AW, Hbb);
  // 13) wo_out = Hb @ wo + b (bf16)  [64x64]
  mm_k<8,0,64,64><<<dim3(8,128), 256, 0, stream>>>(Hbb,512, woT,512, WOUTb,512,
        NROWS,512,512, wo_b,nulf,nulf,nulf,nulh,nulh);
  // 14) attn_out = LN(wo_out(bf16) + xn2(f32)) -> bf16 only
  ln_k<2><<<2048, 256, 0, stream>>>(WOUTb, XN2, nullptr, attn_ln_g, attn_ln_b, nullptr, ATTb);
  // 15) gate fusion -> X1 (x3 in place)  [64x64, bf16 m/at]
  mm_k<6,3,64,64><<<dim3(8,128), 256, 0, stream>>>(MBb,512, gateT,1024, X1,512,
        NROWS,512,1024, gate_b, (const float*)MBb, (const float*)ATTb, X1, ATTb, nulh);
  // 16) xn3b = LN(x3)
  ln_k<0><<<2048, 256, 0, stream>>>(X1, nullptr, nullptr, norm3_g, norm3_b, nullptr, NB);
  // 17) fh = gelu(xn3 @ ffn1 + b1) (bf16)
  mm_k<3,0,128,128><<<dim3(16,64), 256, 0, stream>>>(NB,512, ffn1T,512, FHb,2048,
        NROWS,2048,512, ffn_b1,nulf,nulf,nulf,nulh,nulh);
  // 18) out = x3 + fh @ ffn2 + b2 -> d_out  [64x64]
  mm_k<5,0,64,64><<<dim3(8,128), 256, 0, stream>>>(FHb,2048, ffn2T,2048, XOUT,512,
        NROWS,512,2048, ffn_b2, X1,nulf,nulf,nulh,nulh);
}